// Round 5
// baseline (659.037 us; speedup 1.0000x reference)
//
#include <hip/hip_runtime.h>

#define Bb 128
#define Tt 1024
#define Dd 512
#define Vv 128
#define Ll 128
#define EPSF 1e-7f
#define PADK 72
#define CH 16
#define NEGF -1e30f

typedef float f4 __attribute__((ext_vector_type(4)));
typedef short s8 __attribute__((ext_vector_type(8)));
typedef float f32x4 __attribute__((ext_vector_type(4)));

__device__ inline unsigned int f2bf(float f) {
    unsigned int u = __float_as_uint(f);
    return (u + 0x7fffu + ((u >> 16) & 1u)) >> 16;  // RNE bf16 (no NaN inputs)
}

// logaddexp via hw v_exp_f32/v_log_f32 (__expf/__logf only -- __exp2f/__log2f
// collide with glibc host decls). Inputs in [-1e30, ~0]; never NaN/inf.
__device__ inline float lae2(float x, float y) {
    float m = fmaxf(x, y);
    float d = fminf(x, y) - m;                       // <= 0 (0 when both NEG)
    return m + __logf(1.f + __expf(d));
}
__device__ inline float lae3(float x, float y, float z) {
    float m = fmaxf(fmaxf(x, y), z);
    float s = __expf(x - m) + __expf(y - m) + __expf(z - m);
    return m + __logf(s);
}

// Prep: W [512,128] f32 -> Wt [v][k] bf16 (B^T layout for MFMA B-operand)
__global__ void wt_kernel(const float* __restrict__ W, unsigned short* __restrict__ Wt) {
    int idx = blockIdx.x * 256 + threadIdx.x;   // 65536
    int v = idx >> 9, k = idx & 511;
    Wt[idx] = (unsigned short)f2bf(W[k * Vv + v]);
}

// Fused GEMM (bf16 MFMA) + bias + softmax + log(p+eps): LP[b*t][v]
__global__ __launch_bounds__(256) void gemm_softmax(
    const float* __restrict__ x, const unsigned short* __restrict__ Wt,
    const float* __restrict__ bias, float* __restrict__ LP)
{
    __shared__ float lds[128 * 128];           // 64 KB: staging tiles, then logits in epilogue
    unsigned short* Al = (unsigned short*)lds;         // [128][PADK] bf16
    unsigned short* Bl = Al + 128 * PADK;              // [128][PADK] bf16 (v-major)

    const int tid = threadIdx.x;
    const int wave = tid >> 6, lane = tid & 63;
    const int lm = lane & 15, lq = lane >> 4;
    const int wm = (wave >> 1) << 6, wn = (wave & 1) << 6;
    const long row0 = (long)blockIdx.x << 7;

    f32x4 acc[4][4];
    #pragma unroll
    for (int i = 0; i < 4; i++)
        #pragma unroll
        for (int j = 0; j < 4; j++)
            acc[i][j] = (f32x4){0.f, 0.f, 0.f, 0.f};

    for (int k0 = 0; k0 < Dd; k0 += 64) {
        __syncthreads();
        // stage A: 128 rows x 64 k, f32 -> bf16  (2048 float4)
        #pragma unroll
        for (int i = 0; i < 8; i++) {
            int idx = tid + (i << 8);
            int r = idx >> 4, c4 = idx & 15;
            f4 v = *(const f4*)(x + (row0 + r) * Dd + k0 + (c4 << 2));
            unsigned long long q =
                (unsigned long long)(f2bf(v.x) | (f2bf(v.y) << 16)) |
                ((unsigned long long)(f2bf(v.z) | (f2bf(v.w) << 16)) << 32);
            *(unsigned long long*)(Al + r * PADK + (c4 << 2)) = q;
        }
        // stage B: 128 v-rows x 8 chunks of 8 shorts
        #pragma unroll
        for (int i = 0; i < 4; i++) {
            int idx = tid + (i << 8);
            int vr = idx >> 3, c = idx & 7;
            f4 w = *(const f4*)(Wt + vr * 512 + k0 + (c << 3));
            *(f4*)(Bl + vr * PADK + (c << 3)) = w;
        }
        __syncthreads();
        #pragma unroll
        for (int kk = 0; kk < 64; kk += 32) {
            s8 af[4], bfr[4];
            #pragma unroll
            for (int mi = 0; mi < 4; mi++)
                af[mi] = *(const s8*)(Al + (wm + (mi << 4) + lm) * PADK + kk + (lq << 3));
            #pragma unroll
            for (int ni = 0; ni < 4; ni++)
                bfr[ni] = *(const s8*)(Bl + (wn + (ni << 4) + lm) * PADK + kk + (lq << 3));
            #pragma unroll
            for (int mi = 0; mi < 4; mi++)
                #pragma unroll
                for (int ni = 0; ni < 4; ni++)
                    acc[mi][ni] = __builtin_amdgcn_mfma_f32_16x16x32_bf16(
                        af[mi], bfr[ni], acc[mi][ni], 0, 0, 0);
        }
    }
    __syncthreads();
    // write logits+bias to swizzled LDS (chunk rotation, bijective per row)
    #pragma unroll
    for (int mi = 0; mi < 4; mi++) {
        #pragma unroll
        for (int ni = 0; ni < 4; ni++) {
            int col = wn + (ni << 4) + lm;
            float bv = bias[col];
            #pragma unroll
            for (int r = 0; r < 4; r++) {
                int row = wm + (mi << 4) + (lq << 2) + r;
                int word = (row << 7) + ((((col >> 2) + row) & 31) << 2) + (col & 3);
                lds[word] = acc[mi][ni][r] + bv;
            }
        }
    }
    __syncthreads();
    // per-row softmax -> log(p + eps)
    if (tid < 128) {
        int row = tid;
        float m = -1e30f;
        #pragma unroll
        for (int c = 0; c < 32; c++) {
            int word = (row << 7) + (((c + row) & 31) << 2);
            f4 v = *(const f4*)(lds + word);
            m = fmaxf(m, fmaxf(fmaxf(v.x, v.y), fmaxf(v.z, v.w)));
        }
        float s = 0.f;
        #pragma unroll
        for (int c = 0; c < 32; c++) {
            int word = (row << 7) + (((c + row) & 31) << 2);
            f4 v = *(f4*)(lds + word);
            v.x = __expf(v.x - m); v.y = __expf(v.y - m);
            v.z = __expf(v.z - m); v.w = __expf(v.w - m);
            s += v.x + v.y + v.z + v.w;
            *(f4*)(lds + word) = v;
        }
        float inv = 1.f / s;
        f4* Pout = (f4*)(LP + (row0 + row) * Vv);
        #pragma unroll
        for (int c = 0; c < 32; c++) {
            int word = (row << 7) + (((c + row) & 31) << 2);
            f4 v = *(const f4*)(lds + word);
            v.x = __logf(fmaf(v.x, inv, EPSF));
            v.y = __logf(fmaf(v.y, inv, EPSF));
            v.z = __logf(fmaf(v.z, inv, EPSF));
            v.w = __logf(fmaf(v.w, inv, EPSF));
            Pout[c] = v;
        }
    }
}

// CTC forward DP, LOG domain (exact reference semantics, NEG=-1e30).
// One wave per example; lane i owns states 4i..4i+3; a4 mirrors lane i+1's a0
// (lane 63's a4 = real state 256). Each lane gather-loads its 3 fixed LP
// columns (blank=127, tgt0, tgt1) with a CH-deep prefetch queue; the only
// cross-lane op per step is __shfl_up(a3,1).
__global__ __launch_bounds__(64) void ctc_kernel(
    const float* __restrict__ LP, const int* __restrict__ targets,
    const int* __restrict__ tlen, float* __restrict__ out)
{
    const int b = blockIdx.x;
    const int lane = threadIdx.x;
    const float* Pb = LP + (long)b * Tt * Vv;

    const int tgt0 = targets[(b << 7) + (lane << 1)];
    const int tgt1 = targets[(b << 7) + (lane << 1) + 1];
    int tp = __shfl_up(tgt1, 1);
    if (lane == 0) tp = -1;
    const bool mA = (tgt0 != tp);      // skip allowed into s=4i+1
    const bool mB = (tgt1 != tgt0);    // skip allowed into s=4i+3

    const float* pB = Pb + 127;
    const float* p0 = Pb + tgt0;
    const float* p1 = Pb + tgt1;

    // t = 0: only s=0 (blank) and s=1 (first label) reachable
    float a0 = (lane == 0) ? pB[0] : NEGF;
    float a1 = (lane == 0) ? p0[0] : NEGF;   // lane0's tgt0 == targets[b][0]
    float a2 = NEGF, a3 = NEGF, a4 = NEGF;

    float cb[CH], c0[CH], c1[CH];
    #pragma unroll
    for (int i = 0; i < CH; i++) {
        cb[i] = pB[(1 + i) * Vv];
        c0[i] = p0[(1 + i) * Vv];
        c1[i] = p1[(1 + i) * Vv];
    }

    for (int tb = 1; tb < Tt; tb += CH) {
        float nb[CH], q0[CH], q1[CH];
        #pragma unroll
        for (int i = 0; i < CH; i++) {
            int tn = tb + CH + i; if (tn > Tt - 1) tn = Tt - 1;
            nb[i] = pB[tn * Vv]; q0[i] = p0[tn * Vv]; q1[i] = p1[tn * Vv];
        }
        #pragma unroll
        for (int i = 0; i < CH; i++) {
            if (tb + i < Tt) {
                float lb = cb[i], l0 = c0[i], l1 = c1[i];
                float sa3 = __shfl_up(a3, 1);
                if (lane == 0) sa3 = NEGF;
                float zA = mA ? sa3 : NEGF;
                float zB = mB ? a1  : NEGF;
                float n0 = lae2(a0, sa3)    + lb;
                float n1 = lae3(a0, a1, zA) + l0;
                float n2 = lae2(a1, a2)     + lb;
                float n3 = lae3(a2, a3, zB) + l1;
                float n4 = lae2(a3, a4)     + lb;
                a0 = n0; a1 = n1; a2 = n2; a3 = n3; a4 = n4;
            }
        }
        #pragma unroll
        for (int i = 0; i < CH; i++) { cb[i] = nb[i]; c0[i] = q0[i]; c1[i] = q1[i]; }
    }

    __shared__ float af[257];
    af[(lane << 2) + 0] = a0; af[(lane << 2) + 1] = a1;
    af[(lane << 2) + 2] = a2; af[(lane << 2) + 3] = a3;
    if (lane == 63) af[256] = a4;
    __syncthreads();
    if (lane == 0) {
        int len = tlen[b];
        float loss = -lae2(af[2 * len], af[2 * len - 1]);
        atomicAdd(out, loss);
    }
}

extern "C" void kernel_launch(void* const* d_in, const int* in_sizes, int n_in,
                              void* d_out, int out_size, void* d_ws, size_t ws_size,
                              hipStream_t stream) {
    const float* x       = (const float*)d_in[0];
    const float* W       = (const float*)d_in[1];
    const float* bias    = (const float*)d_in[2];
    const int*   targets = (const int*)d_in[3];
    const int*   tl      = (const int*)d_in[4];
    float* out = (float*)d_out;

    float* LP = (float*)d_ws;                                      // 64 MB log-probs
    unsigned short* Wt = (unsigned short*)((char*)d_ws + (size_t)Bb * Tt * Vv * 4);

    (void)hipMemsetAsync(out, 0, sizeof(float), stream);
    wt_kernel<<<256, 256, 0, stream>>>(W, Wt);
    gemm_softmax<<<1024, 256, 0, stream>>>(x, Wt, bias, LP);
    ctc_kernel<<<Bb, 64, 0, stream>>>(LP, targets, tl, out);
}